// Round 4
// baseline (2908.902 us; speedup 1.0000x reference)
//
#include <hip/hip_runtime.h>

#define BB   32
#define TT   2048
#define HH   256
#define G3   768      // 3*H
#define NVOC 18       // vocab rows (V+2)
#define NOUT 17       // head outputs (V+1)
#define LOGITS_ELEMS ((size_t)BB * TT * NOUT)

typedef _Float16 h2 __attribute__((ext_vector_type(2)));

__device__ __forceinline__ float bf1(unsigned short u){
  union{unsigned int i; float f;} v; v.i = ((unsigned int)u) << 16; return v.f;
}
__device__ __forceinline__ unsigned short f2bf(float f){
  union{float f; unsigned int i;} v; v.f = f;
  unsigned int lsb = (v.i >> 16) & 1u;
  v.i += 0x7fffu + lsb;               // round-to-nearest-even
  return (unsigned short)(v.i >> 16);
}

__device__ __forceinline__ float ld1(const float* p, size_t i){ return p[i]; }
__device__ __forceinline__ float ld1(const unsigned short* p, size_t i){ return bf1(p[i]); }

// Device-side dtype detection: W_ih ~ uniform(-1/16,1/16). If the buffer is
// f32, low-half words decode as bf16 with random exponents -> some |v|>0.25.
__device__ __forceinline__ bool detect_f32(const void* W_ih_raw){
  const unsigned short* u = (const unsigned short*)W_ih_raw;
  bool big = false;
  #pragma unroll
  for (int i = 0; i < 64; i++){
    float v = bf1(u[i]);
    big |= !(v >= -0.25f && v <= 0.25f);
  }
  return big;
}

#if __has_builtin(__builtin_amdgcn_fdot2)
#define FDOT2(a,b,c) __builtin_amdgcn_fdot2((a),(b),(c),false)
#else
#define FDOT2(a,b,c) ((c) + (float)(a).x*(float)(b).x + (float)(a).y*(float)(b).y)
#endif

__device__ __forceinline__ h2 bch2(unsigned int u){ return __builtin_bit_cast(h2, u); }

// single-instruction packed dot: acc += w.lo*x.lo + w.hi*x.hi (f16 pairs,
// f32 accumulate). Bypasses any multi-op lowering of the builtin.
__device__ __forceinline__ void dot2a(float& acc, float w, int x){
  asm("v_dot2_f32_f16 %0, %1, %2, %0" : "+v"(acc) : "v"(w), "v"(x));
}

// DPP quad shuffles (pure VALU, no LDS round-trip)
__device__ __forceinline__ float dppB1(float v){    // quad_perm(1,0,3,2): xor1
  int i = __builtin_bit_cast(int, v);
  i = __builtin_amdgcn_mov_dpp(i, 0xB1, 0xF, 0xF, true);
  return __builtin_bit_cast(float, i);
}
__device__ __forceinline__ float dpp4E(float v){    // quad_perm(2,3,0,1): xor2
  int i = __builtin_bit_cast(int, v);
  i = __builtin_amdgcn_mov_dpp(i, 0x4E, 0xF, 0xF, true);
  return __builtin_bit_cast(float, i);
}

// raw barrier: LDS-visibility only. Skips __syncthreads()'s vmcnt(0) drain so
// per-step global stores (outs/betas, never read back in-kernel) stay
// fire-and-forget instead of stalling every iteration.
__device__ __forceinline__ void bar_lds(){
  asm volatile("s_waitcnt lgkmcnt(0)\n\ts_barrier" ::: "memory");
}

// ---------------------------------------------------------------------------
// k_prep: pack W_hh for k_scan's quad-ownership layout.
// k_scan thread tid (a=tid>>2, lq=tid&3) owns hidden-unit pair {2a, 2a+1}
// for all 3 gates, k-range [64*lq, 64*lq+64).
// Weight reg (gi, jx), gi = 2*gate + i (i = unit sub-index), jx = 0..7:
//   float4 = 4 h2 k-pairs; pair c = ( W_hh[k0+2c][col], W_hh[k0+2c+1][col] ),
//   k0 = 64*lq + 8*jx, col = 256*gate + 2a + i.
// Flat: Wp4[(gi*8 + jx)*512 + tid]; prep thread s (96x256 grid) writes Wp4[s].
// ---------------------------------------------------------------------------
template<typename T>
__device__ __forceinline__ void prep_body(const T* W_hh, float4* Wp4){
  int s   = blockIdx.x * 256 + threadIdx.x;    // 0..24575
  int tid = s & 511;
  int r9  = s >> 9;                            // 0..47
  int jx  = r9 & 7, gi = r9 >> 3;              // gi 0..5
  int g   = gi >> 1, ii = gi & 1;
  int a   = tid >> 2, lq = tid & 3;
  int col = (g << 8) + (a << 1) + ii;
  int k0  = (lq << 6) + (jx << 3);
  float c0, c1, c2, c3;
  #pragma unroll
  for (int c = 0; c < 4; c++){
    h2 pr;
    pr.x = (_Float16)ld1(W_hh, (size_t)(k0 + 2*c    ) * G3 + col);
    pr.y = (_Float16)ld1(W_hh, (size_t)(k0 + 2*c + 1) * G3 + col);
    float fc = __builtin_bit_cast(float, pr);
    if (c == 0) c0 = fc; else if (c == 1) c1 = fc;
    else if (c == 2) c2 = fc; else c3 = fc;
  }
  float4 v; v.x = c0; v.y = c1; v.z = c2; v.w = c3;
  Wp4[s] = v;
}

__global__ __launch_bounds__(256) void k_prep(
    const void* __restrict__ W_hh, const void* __restrict__ W_ih,
    float4* __restrict__ Wp4)
{
  if (detect_f32(W_ih)) prep_body<float>((const float*)W_hh, Wp4);
  else                  prep_body<unsigned short>((const unsigned short*)W_hh, Wp4);
}

// ---------------------------------------------------------------------------
// k_proj: proj[v][j] = b_ih[j] + sum_k embed[v][k]*W_ih[k][j]. Block = one v,
// 768 threads, coalesced W_ih reads. Block 0 also converts b_hh -> f32 bb[].
// ---------------------------------------------------------------------------
template<typename T>
__device__ __forceinline__ void proj_body(const T* embed, const T* W_ih,
                                          const T* b_ih, const T* b_hh,
                                          float* proj, float* bb){
  __shared__ float s_e[HH];
  int v = blockIdx.x, j = threadIdx.x;
  if (j < HH) s_e[j] = ld1(embed, (size_t)v * HH + j);
  if (v == 0) bb[j] = ld1(b_hh, (size_t)j);
  __syncthreads();
  float acc = ld1(b_ih, (size_t)j);
  #pragma unroll 8
  for (int k = 0; k < HH; k++)
    acc += s_e[k] * ld1(W_ih, (size_t)k * G3 + j);
  proj[(size_t)v * G3 + j] = acc;
}

__global__ __launch_bounds__(768) void k_proj(
    const void* __restrict__ embed, const void* __restrict__ W_ih,
    const void* __restrict__ b_ih, const void* __restrict__ b_hh,
    float* __restrict__ proj, float* __restrict__ bb)
{
  if (detect_f32(W_ih))
    proj_body<float>((const float*)embed, (const float*)W_ih,
                     (const float*)b_ih, (const float*)b_hh, proj, bb);
  else
    proj_body<unsigned short>((const unsigned short*)embed,
                              (const unsigned short*)W_ih,
                              (const unsigned short*)b_ih,
                              (const unsigned short*)b_hh, proj, bb);
}

// ---------------------------------------------------------------------------
// k_scan: GRU scan, 512 threads (8 waves), one block per batch element.
// Quad (lanes 4a..4a+3) owns hidden-unit pair {2a,2a+1}; lane lq covers
// k in [64lq, 64lq+64). 192 v_dot2_f32_f16/thread; weights in 48 float4
// PINNED through a volatile asm (un-sinkable, un-rematerializable) so the
// 192 weight VGPRs stay live across the whole scan -- v2/v3 let LLVM sink
// the loads back into the loop (VGPR=120, FETCH 1.9GB/dispatch observed).
// Quad DPP reduction; gate chain per lane; one lgkm-only barrier per step;
// s_h double-buffered + XOR line-swizzled (4 k-quarter lines -> disjoint
// bank quads).
// ---------------------------------------------------------------------------

// X-macro over the 48 weight registers
#define FORJX(M, g, i, base) \
  M(g,i,0,(base)+0) M(g,i,1,(base)+1) M(g,i,2,(base)+2) M(g,i,3,(base)+3) \
  M(g,i,4,(base)+4) M(g,i,5,(base)+5) M(g,i,6,(base)+6) M(g,i,7,(base)+7)
#define FORALLW(M) \
  FORJX(M,r,0,0)  FORJX(M,r,1,8)  FORJX(M,z,0,16) \
  FORJX(M,z,1,24) FORJX(M,n,0,32) FORJX(M,n,1,40)

// load + PIN: volatile asm output cannot be sunk into the loop or re-executed,
// so the value must stay register-resident for its whole live range.
#define DECLW(g,i,jx,idx) \
  float4 w_##g##i##_##jx = wp[(idx)*512]; \
  asm volatile("" : "+v"(w_##g##i##_##jx.x), "+v"(w_##g##i##_##jx.y), \
                    "+v"(w_##g##i##_##jx.z), "+v"(w_##g##i##_##jx.w));

#define DOTJ(jx) { \
  int4 hv = hp[hix##jx]; \
  dot2a(ar0, w_r0_##jx.x, hv.x); dot2a(ar1, w_r1_##jx.x, hv.x); \
  dot2a(az0, w_z0_##jx.x, hv.x); dot2a(az1, w_z1_##jx.x, hv.x); \
  dot2a(an0, w_n0_##jx.x, hv.x); dot2a(an1, w_n1_##jx.x, hv.x); \
  dot2a(ar0, w_r0_##jx.y, hv.y); dot2a(ar1, w_r1_##jx.y, hv.y); \
  dot2a(az0, w_z0_##jx.y, hv.y); dot2a(az1, w_z1_##jx.y, hv.y); \
  dot2a(an0, w_n0_##jx.y, hv.y); dot2a(an1, w_n1_##jx.y, hv.y); \
  dot2a(ar0, w_r0_##jx.z, hv.z); dot2a(ar1, w_r1_##jx.z, hv.z); \
  dot2a(az0, w_z0_##jx.z, hv.z); dot2a(az1, w_z1_##jx.z, hv.z); \
  dot2a(an0, w_n0_##jx.z, hv.z); dot2a(an1, w_n1_##jx.z, hv.z); \
  dot2a(ar0, w_r0_##jx.w, hv.w); dot2a(ar1, w_r1_##jx.w, hv.w); \
  dot2a(az0, w_z0_##jx.w, hv.w); dot2a(az1, w_z1_##jx.w, hv.w); \
  dot2a(an0, w_n0_##jx.w, hv.w); dot2a(an1, w_n1_##jx.w, hv.w); }

__global__ __launch_bounds__(512, 2) void k_scan(
    const int*    __restrict__ tokens,
    const float4* __restrict__ Wp4,    // prepped weights
    const float*  __restrict__ bb,     // b_hh as f32
    const void*   __restrict__ W_ih,   // dtype detection (betas store)
    const float*  __restrict__ proj,
    _Float16*     __restrict__ outs,   // [B,T,H] f16 scratch
    void*         __restrict__ d_out_base)
{
  __shared__ float s_proj[NVOC * G3];            // 55296 B
  __shared__ int   s_tok[TT];                    //  8192 B
  __shared__ __align__(16) _Float16 s_h[2][HH];  //  1024 B dbuf h (swizzled)

  const bool f32m = detect_f32(W_ih);
  const int b   = blockIdx.x;
  const int tid = threadIdx.x;     // 0..511
  const int a   = tid >> 2;        // unit-pair 0..127 -> units {2a, 2a+1}
  const int lq  = tid & 3;         // k-quarter
  const int sel = lq >> 1;         // this lane's gate unit: 2a + sel
  const int u   = 2*a + sel;

  // stage proj (3456 float4) and tokens (512 int4); zero both h buffers
  for (int i = tid; i < NVOC * G3 / 4; i += 512)
    ((float4*)s_proj)[i] = ((const float4*)proj)[i];
  ((int4*)s_tok)[tid] = ((const int4*)(tokens + (size_t)b * TT))[tid];
  if (tid < 256) ((int*)s_h)[tid] = 0;

  // 48 pinned weight registers (192 VGPRs)
  const float4* wp = Wp4 + tid;
  FORALLW(DECLW)

  // biases for this lane's unit
  const float bhr = bb[u];
  const float bhz = bb[HH + u];
  const float bhn = bb[2*HH + u];

  // swizzle: logical 16B line L (of 32 per buffer) lives at physical line
  // (L&24) | ((L&7) ^ (L>>3)).  Reader line for (lq,jx): L = 8lq+jx ->
  // phys = 8lq | (jx^lq)  (disjoint bank-quads across lq).  Writer dword a:
  int pa;
  {
    int Ld = a >> 2, md = a >> 5;
    pa = (((Ld & 24) | ((Ld & 7) ^ md)) << 2) | (a & 3);
  }
  const int hb = lq << 3;
  const int hix0 = hb | (0 ^ lq), hix1 = hb | (1 ^ lq), hix2 = hb | (2 ^ lq),
            hix3 = hb | (3 ^ lq), hix4 = hb | (4 ^ lq), hix5 = hb | (5 ^ lq),
            hix6 = hb | (6 ^ lq), hix7 = hb | (7 ^ lq);

  float h_old = 0.f;               // h[u]

  unsigned* orow_u = (unsigned*)outs + (((size_t)b * TT * HH) >> 1) + a;
  unsigned* brow_u = (unsigned*)((unsigned short*)d_out_base + LOGITS_ELEMS)
                     + (((size_t)b * TT * HH) >> 1) + a;
  float2*   brow_f = (float2*)((float*)d_out_base + LOGITS_ELEMS)
                     + (((size_t)b * TT * HH) >> 1) + a;

  __syncthreads();   // staging + weight loads settled (one-time full drain)

  for (int t = 0; t < TT; t++) {
    int tok = s_tok[t];
    const float* pj = s_proj + tok * G3;
    float gir = pj[u];
    float giz = pj[HH + u];
    float gin = pj[2*HH + u];

    const int4* hp = (const int4*)(&s_h[t & 1][0]);

    float ar0=0.f, ar1=0.f, az0=0.f, az1=0.f, an0=0.f, an1=0.f;
    DOTJ(0) DOTJ(1) DOTJ(2) DOTJ(3) DOTJ(4) DOTJ(5) DOTJ(6) DOTJ(7)

    // own-unit / other-unit partial selection, then quad reduction:
    // step 1 (xor2 via 0x4E): my k-quarter + partner's k-quarter of MY unit
    // step 2 (xor1 via 0xB1): combine the two k-halves
    float pr = sel ? ar1 : ar0,  qr = sel ? ar0 : ar1;
    float pz = sel ? az1 : az0,  qz = sel ? az0 : az1;
    float pn = sel ? an1 : an0,  qn = sel ? an0 : an1;
    pr += dpp4E(qr);  pz += dpp4E(qz);  pn += dpp4E(qn);
    pr += dppB1(pr);  pz += dppB1(pz);  pn += dppB1(pn);

    // gate chain, once per lane for unit u
    float r = 1.f / (1.f + __expf(-(gir + pr + bhr)));
    float z = 1.f / (1.f + __expf(-(giz + pz + bhz)));
    float x = gin + r * (pn + bhn);
    x = fminf(fmaxf(x, -15.f), 15.f);
    float e = __expf(2.f * x);
    float n = (e - 1.f) / (e + 1.f);     // tanh
    float hn = (1.f - z) * n + z * h_old;
    h_old = hn;

    // cross-lane partner values for packed stores
    float hn_o = dpp4E(hn);              // other unit's hn
    float z_o  = dpp4E(z);               // other unit's z

    if (lq == 0) {                       // publish h pair {u0,u1} (swizzled)
      h2 ph; ph.x = (_Float16)hn; ph.y = (_Float16)hn_o;
      ((unsigned*)(&s_h[(t + 1) & 1][0]))[pa] = __builtin_bit_cast(unsigned, ph);
    } else if (lq == 2) {                // outs f16 pair {u0,u1}
      h2 po; po.x = (_Float16)hn_o; po.y = (_Float16)hn;
      orow_u[(size_t)t * (HH/2)] = __builtin_bit_cast(unsigned, po);
    } else if (lq == 1) {                // beta pair {u0,u1}
      if (f32m) { float2 fz; fz.x = z; fz.y = z_o;
                  brow_f[(size_t)t * (HH/2)] = fz; }
      else      { unsigned pz2 = (unsigned)f2bf(z) | ((unsigned)f2bf(z_o) << 16);
                  brow_u[(size_t)t * (HH/2)] = pz2; }
    }
    bar_lds();   // lgkmcnt(0)+s_barrier; global stores stay in flight
  }
}

// ---------------------------------------------------------------------------
// k_head: logits = outs @ W_head + b_head.  outs is f16; W_head staged to LDS
// as packed h2 pairs (stride 129 h2 per output column -> no bank conflicts),
// inner loop is 128 fdot2.
// ---------------------------------------------------------------------------
#define WSTR 129

template<typename T>
__device__ __forceinline__ void stage_head(const T* W_head, const T* b_head,
                                           h2* s_w, float* s_b, int tid){
  for (int i = tid; i < NOUT * 128; i += 256) {
    int o = i >> 7, ip = i & 127;
    h2 pr;
    pr.x = (_Float16)ld1(W_head, (size_t)(2*ip    ) * NOUT + o);
    pr.y = (_Float16)ld1(W_head, (size_t)(2*ip + 1) * NOUT + o);
    s_w[o * WSTR + ip] = pr;
  }
  if (tid < NOUT) s_b[tid] = ld1(b_head, (size_t)tid);
}

__global__ __launch_bounds__(256) void k_head(
    const _Float16* __restrict__ outs,
    const void* __restrict__ W_head,
    const void* __restrict__ b_head,
    const void* __restrict__ W_ih,
    void* __restrict__ logits_out)
{
  __shared__ h2 s_w[NOUT * WSTR];
  __shared__ float s_b[NOUT];
  const bool f32m = detect_f32(W_ih);
  const int tid = threadIdx.x;

  if (f32m) stage_head<float>((const float*)W_head, (const float*)b_head,
                              s_w, s_b, tid);
  else      stage_head<unsigned short>((const unsigned short*)W_head,
                                       (const unsigned short*)b_head,
                                       s_w, s_b, tid);
  __syncthreads();

  size_t gid = (size_t)blockIdx.x * 256 + tid;
  if (gid >= LOGITS_ELEMS) return;
  int o = (int)(gid % NOUT);
  size_t row = gid / NOUT;

  const uint4* xp = (const uint4*)(outs + row * HH);
  const h2* wv = s_w + o * WSTR;
  float a0 = 0.f, a1 = 0.f, a2 = 0.f, a3 = 0.f;
  #pragma unroll 8
  for (int kk = 0; kk < 32; kk++) {
    uint4 uu = xp[kk];
    int kb = kk * 4;
    a0 = FDOT2(bch2(uu.x), wv[kb+0], a0);
    a1 = FDOT2(bch2(uu.y), wv[kb+1], a1);
    a2 = FDOT2(bch2(uu.z), wv[kb+2], a2);
    a3 = FDOT2(bch2(uu.w), wv[kb+3], a3);
  }
  float val = ((a0 + a1) + (a2 + a3)) + s_b[o];
  if (f32m) ((float*)logits_out)[gid] = val;
  else      ((unsigned short*)logits_out)[gid] = f2bf(val);
}

// ---------------------------------------------------------------------------
extern "C" void kernel_launch(void* const* d_in, const int* in_sizes, int n_in,
                              void* d_out, int out_size, void* d_ws, size_t ws_size,
                              hipStream_t stream)
{
  // inputs: tokens, embed, W_ih, W_hh, b_ih, b_hh, W_head, b_head
  const int* tokens = (const int*)d_in[0];
  const void* embed  = d_in[1];
  const void* W_ih   = d_in[2];
  const void* W_hh   = d_in[3];
  const void* b_ih   = d_in[4];
  const void* b_hh   = d_in[5];
  const void* W_head = d_in[6];
  const void* b_head = d_in[7];

  // workspace layout (16B aligned):
  // proj: 13824 f32 = 55296 B | bb: 768 f32 = 3072 B | Wp: 24576 float4 = 393216 B | outs (f16)
  char* ws = (char*)d_ws;
  float*    proj = (float*)ws;
  float*    bb   = (float*)(ws + 55296);
  float4*   Wp4  = (float4*)(ws + 55296 + 3072);
  _Float16* outs = (_Float16*)(ws + 55296 + 3072 + 393216);

  k_prep<<<96, 256, 0, stream>>>(W_hh, W_ih, Wp4);
  k_proj<<<NVOC, G3, 0, stream>>>(embed, W_ih, b_ih, b_hh, proj, bb);
  k_scan<<<BB, 512, 0, stream>>>(tokens, Wp4, bb, W_ih, proj, outs, d_out);
  k_head<<<(int)((LOGITS_ELEMS + 255) / 256), 256, 0, stream>>>(
      outs, W_head, b_head, W_ih, d_out);
}

// Round 5
// 2787.052 us; speedup vs baseline: 1.0437x; 1.0437x over previous
//
#include <hip/hip_runtime.h>

#define BB   32
#define TT   2048
#define HH   256
#define G3   768      // 3*H
#define NVOC 18       // vocab rows (V+2)
#define NOUT 17       // head outputs (V+1)
#define LOGITS_ELEMS ((size_t)BB * TT * NOUT)

typedef _Float16 h2 __attribute__((ext_vector_type(2)));

__device__ __forceinline__ float bf1(unsigned short u){
  union{unsigned int i; float f;} v; v.i = ((unsigned int)u) << 16; return v.f;
}
__device__ __forceinline__ unsigned short f2bf(float f){
  union{float f; unsigned int i;} v; v.f = f;
  unsigned int lsb = (v.i >> 16) & 1u;
  v.i += 0x7fffu + lsb;               // round-to-nearest-even
  return (unsigned short)(v.i >> 16);
}

__device__ __forceinline__ float ld1(const float* p, size_t i){ return p[i]; }
__device__ __forceinline__ float ld1(const unsigned short* p, size_t i){ return bf1(p[i]); }

// Device-side dtype detection: W_ih ~ uniform(-1/16,1/16). If the buffer is
// f32, low-half words decode as bf16 with random exponents -> some |v|>0.25.
__device__ __forceinline__ bool detect_f32(const void* W_ih_raw){
  const unsigned short* u = (const unsigned short*)W_ih_raw;
  bool big = false;
  #pragma unroll
  for (int i = 0; i < 64; i++){
    float v = bf1(u[i]);
    big |= !(v >= -0.25f && v <= 0.25f);
  }
  return big;
}

#if __has_builtin(__builtin_amdgcn_fdot2)
#define FDOT2(a,b,c) __builtin_amdgcn_fdot2((a),(b),(c),false)
#else
#define FDOT2(a,b,c) ((c) + (float)(a).x*(float)(b).x + (float)(a).y*(float)(b).y)
#endif

__device__ __forceinline__ h2 bch2(unsigned int u){ return __builtin_bit_cast(h2, u); }
__device__ __forceinline__ h2 bch2f(float f){ return __builtin_bit_cast(h2, f); }

// DPP quad shuffles (pure VALU, no LDS round-trip)
__device__ __forceinline__ float dppB1(float v){    // quad_perm(1,0,3,2): xor1
  int i = __builtin_bit_cast(int, v);
  i = __builtin_amdgcn_mov_dpp(i, 0xB1, 0xF, 0xF, true);
  return __builtin_bit_cast(float, i);
}
__device__ __forceinline__ float dpp4E(float v){    // quad_perm(2,3,0,1): xor2
  int i = __builtin_bit_cast(int, v);
  i = __builtin_amdgcn_mov_dpp(i, 0x4E, 0xF, 0xF, true);
  return __builtin_bit_cast(float, i);
}

// raw barrier: LDS-visibility only. Skips __syncthreads()'s vmcnt(0) drain so
// per-step global stores (outs/betas, never read back in-kernel) stay
// fire-and-forget instead of stalling every iteration.
__device__ __forceinline__ void bar_lds(){
  asm volatile("s_waitcnt lgkmcnt(0)\n\ts_barrier" ::: "memory");
}

// ---------------------------------------------------------------------------
// k_prep: pack W_hh for k_scan's quad-ownership layout.
// k_scan thread tid (a=tid>>2, lq=tid&3) owns hidden-unit pair {2a, 2a+1}
// for all 3 gates, k-range [64*lq, 64*lq+64).
// Weight reg (gi, jx), gi = 2*gate + i (i = unit sub-index), jx = 0..7:
//   float4 = 4 h2 k-pairs; pair c = ( W_hh[k0+2c][col], W_hh[k0+2c+1][col] ),
//   k0 = 64*lq + 8*jx, col = 256*gate + 2a + i.
// Flat: Wp4[(gi*8 + jx)*512 + tid]; prep thread s (96x256 grid) writes Wp4[s].
// ---------------------------------------------------------------------------
template<typename T>
__device__ __forceinline__ void prep_body(const T* W_hh, float4* Wp4){
  int s   = blockIdx.x * 256 + threadIdx.x;    // 0..24575
  int tid = s & 511;
  int r9  = s >> 9;                            // 0..47
  int jx  = r9 & 7, gi = r9 >> 3;              // gi 0..5
  int g   = gi >> 1, ii = gi & 1;
  int a   = tid >> 2, lq = tid & 3;
  int col = (g << 8) + (a << 1) + ii;
  int k0  = (lq << 6) + (jx << 3);
  float c0, c1, c2, c3;
  #pragma unroll
  for (int c = 0; c < 4; c++){
    h2 pr;
    pr.x = (_Float16)ld1(W_hh, (size_t)(k0 + 2*c    ) * G3 + col);
    pr.y = (_Float16)ld1(W_hh, (size_t)(k0 + 2*c + 1) * G3 + col);
    float fc = __builtin_bit_cast(float, pr);
    if (c == 0) c0 = fc; else if (c == 1) c1 = fc;
    else if (c == 2) c2 = fc; else c3 = fc;
  }
  float4 v; v.x = c0; v.y = c1; v.z = c2; v.w = c3;
  Wp4[s] = v;
}

__global__ __launch_bounds__(256) void k_prep(
    const void* __restrict__ W_hh, const void* __restrict__ W_ih,
    float4* __restrict__ Wp4)
{
  if (detect_f32(W_ih)) prep_body<float>((const float*)W_hh, Wp4);
  else                  prep_body<unsigned short>((const unsigned short*)W_hh, Wp4);
}

// ---------------------------------------------------------------------------
// k_proj: proj[v][j] = b_ih[j] + sum_k embed[v][k]*W_ih[k][j]. Block = one v,
// 768 threads, coalesced W_ih reads. Block 0 also converts b_hh -> f32 bb[].
// ---------------------------------------------------------------------------
template<typename T>
__device__ __forceinline__ void proj_body(const T* embed, const T* W_ih,
                                          const T* b_ih, const T* b_hh,
                                          float* proj, float* bb){
  __shared__ float s_e[HH];
  int v = blockIdx.x, j = threadIdx.x;
  if (j < HH) s_e[j] = ld1(embed, (size_t)v * HH + j);
  if (v == 0) bb[j] = ld1(b_hh, (size_t)j);
  __syncthreads();
  float acc = ld1(b_ih, (size_t)j);
  #pragma unroll 8
  for (int k = 0; k < HH; k++)
    acc += s_e[k] * ld1(W_ih, (size_t)k * G3 + j);
  proj[(size_t)v * G3 + j] = acc;
}

__global__ __launch_bounds__(768) void k_proj(
    const void* __restrict__ embed, const void* __restrict__ W_ih,
    const void* __restrict__ b_ih, const void* __restrict__ b_hh,
    float* __restrict__ proj, float* __restrict__ bb)
{
  if (detect_f32(W_ih))
    proj_body<float>((const float*)embed, (const float*)W_ih,
                     (const float*)b_ih, (const float*)b_hh, proj, bb);
  else
    proj_body<unsigned short>((const unsigned short*)embed,
                              (const unsigned short*)W_ih,
                              (const unsigned short*)b_ih,
                              (const unsigned short*)b_hh, proj, bb);
}

// ---------------------------------------------------------------------------
// k_scan: GRU scan, 512 threads (8 waves), one block per batch element.
// Quad (lanes 4a..4a+3) owns hidden-unit pair {2a,2a+1}; lane lq covers
// k in [64lq, 64lq+64). 192 fdot2/thread; weights in 48 float4 (192 VGPRs).
//
// KEY: amdgpu_waves_per_eu(2,2). __launch_bounds__'s 2nd arg is only a MIN;
// the allocator's default heuristic targeted 4 waves/EU (VGPR=120 observed)
// and spilled/sank the weight file to get occupancy that can never exist
// (grid = 32 blocks = 1 block/CU). Capping max waves/EU at 2 gives the
// allocator the full 256-VGPR budget so the weights stay register-resident.
//
// Quad DPP reduction; gate chain per lane; one lgkm-only barrier per step;
// s_h double-buffered + XOR line-swizzled (4 k-quarter lines -> disjoint
// bank quads).
// ---------------------------------------------------------------------------

// X-macro over the 48 weight registers
#define FORJX(M, g, i, base) \
  M(g,i,0,(base)+0) M(g,i,1,(base)+1) M(g,i,2,(base)+2) M(g,i,3,(base)+3) \
  M(g,i,4,(base)+4) M(g,i,5,(base)+5) M(g,i,6,(base)+6) M(g,i,7,(base)+7)
#define FORALLW(M) \
  FORJX(M,r,0,0)  FORJX(M,r,1,8)  FORJX(M,z,0,16) \
  FORJX(M,z,1,24) FORJX(M,n,0,32) FORJX(M,n,1,40)

// load + PIN: volatile asm output cannot be sunk into the loop or re-executed.
#define DECLW(g,i,jx,idx) \
  float4 w_##g##i##_##jx = wp[(idx)*512]; \
  asm volatile("" : "+v"(w_##g##i##_##jx.x), "+v"(w_##g##i##_##jx.y), \
                    "+v"(w_##g##i##_##jx.z), "+v"(w_##g##i##_##jx.w));

#define DOTJ(jx) { \
  int4 hv = hp[hix##jx]; \
  h2 x0 = bch2((unsigned)hv.x), x1 = bch2((unsigned)hv.y), \
     x2 = bch2((unsigned)hv.z), x3 = bch2((unsigned)hv.w); \
  ar0 = FDOT2(bch2f(w_r0_##jx.x), x0, ar0); \
  ar1 = FDOT2(bch2f(w_r1_##jx.x), x0, ar1); \
  az0 = FDOT2(bch2f(w_z0_##jx.x), x0, az0); \
  az1 = FDOT2(bch2f(w_z1_##jx.x), x0, az1); \
  an0 = FDOT2(bch2f(w_n0_##jx.x), x0, an0); \
  an1 = FDOT2(bch2f(w_n1_##jx.x), x0, an1); \
  ar0 = FDOT2(bch2f(w_r0_##jx.y), x1, ar0); \
  ar1 = FDOT2(bch2f(w_r1_##jx.y), x1, ar1); \
  az0 = FDOT2(bch2f(w_z0_##jx.y), x1, az0); \
  az1 = FDOT2(bch2f(w_z1_##jx.y), x1, az1); \
  an0 = FDOT2(bch2f(w_n0_##jx.y), x1, an0); \
  an1 = FDOT2(bch2f(w_n1_##jx.y), x1, an1); \
  ar0 = FDOT2(bch2f(w_r0_##jx.z), x2, ar0); \
  ar1 = FDOT2(bch2f(w_r1_##jx.z), x2, ar1); \
  az0 = FDOT2(bch2f(w_z0_##jx.z), x2, az0); \
  az1 = FDOT2(bch2f(w_z1_##jx.z), x2, az1); \
  an0 = FDOT2(bch2f(w_n0_##jx.z), x2, an0); \
  an1 = FDOT2(bch2f(w_n1_##jx.z), x2, an1); \
  ar0 = FDOT2(bch2f(w_r0_##jx.w), x3, ar0); \
  ar1 = FDOT2(bch2f(w_r1_##jx.w), x3, ar1); \
  az0 = FDOT2(bch2f(w_z0_##jx.w), x3, az0); \
  az1 = FDOT2(bch2f(w_z1_##jx.w), x3, az1); \
  an0 = FDOT2(bch2f(w_n0_##jx.w), x3, an0); \
  an1 = FDOT2(bch2f(w_n1_##jx.w), x3, an1); }

__global__
__attribute__((amdgpu_flat_work_group_size(512, 512), amdgpu_waves_per_eu(2, 2)))
void k_scan(
    const int*    __restrict__ tokens,
    const float4* __restrict__ Wp4,    // prepped weights
    const float*  __restrict__ bb,     // b_hh as f32
    const void*   __restrict__ W_ih,   // dtype detection (betas store)
    const float*  __restrict__ proj,
    _Float16*     __restrict__ outs,   // [B,T,H] f16 scratch
    void*         __restrict__ d_out_base)
{
  __shared__ float s_proj[NVOC * G3];            // 55296 B
  __shared__ int   s_tok[TT];                    //  8192 B
  __shared__ __align__(16) _Float16 s_h[2][HH];  //  1024 B dbuf h (swizzled)

  const bool f32m = detect_f32(W_ih);
  const int b   = blockIdx.x;
  const int tid = threadIdx.x;     // 0..511
  const int a   = tid >> 2;        // unit-pair 0..127 -> units {2a, 2a+1}
  const int lq  = tid & 3;         // k-quarter
  const int sel = lq >> 1;         // this lane's gate unit: 2a + sel
  const int u   = 2*a + sel;

  // stage proj (3456 float4) and tokens (512 int4); zero both h buffers
  for (int i = tid; i < NVOC * G3 / 4; i += 512)
    ((float4*)s_proj)[i] = ((const float4*)proj)[i];
  ((int4*)s_tok)[tid] = ((const int4*)(tokens + (size_t)b * TT))[tid];
  if (tid < 256) ((int*)s_h)[tid] = 0;

  // 48 pinned weight registers (192 VGPRs)
  const float4* wp = Wp4 + tid;
  FORALLW(DECLW)

  // biases for this lane's unit
  const float bhr = bb[u];
  const float bhz = bb[HH + u];
  const float bhn = bb[2*HH + u];

  // swizzle: logical 16B line L (of 32 per buffer) lives at physical line
  // (L&24) | ((L&7) ^ (L>>3)).  Reader line for (lq,jx): L = 8lq+jx ->
  // phys = 8lq | (jx^lq)  (disjoint bank-quads across lq).  Writer dword a:
  int pa;
  {
    int Ld = a >> 2, md = a >> 5;
    pa = (((Ld & 24) | ((Ld & 7) ^ md)) << 2) | (a & 3);
  }
  const int hb = lq << 3;
  const int hix0 = hb | (0 ^ lq), hix1 = hb | (1 ^ lq), hix2 = hb | (2 ^ lq),
            hix3 = hb | (3 ^ lq), hix4 = hb | (4 ^ lq), hix5 = hb | (5 ^ lq),
            hix6 = hb | (6 ^ lq), hix7 = hb | (7 ^ lq);

  float h_old = 0.f;               // h[u]

  unsigned* orow_u = (unsigned*)outs + (((size_t)b * TT * HH) >> 1) + a;
  unsigned* brow_u = (unsigned*)((unsigned short*)d_out_base + LOGITS_ELEMS)
                     + (((size_t)b * TT * HH) >> 1) + a;
  float2*   brow_f = (float2*)((float*)d_out_base + LOGITS_ELEMS)
                     + (((size_t)b * TT * HH) >> 1) + a;

  __syncthreads();   // staging + weight loads settled (one-time full drain)

  for (int t = 0; t < TT; t++) {
    int tok = s_tok[t];
    const float* pj = s_proj + tok * G3;
    float gir = pj[u];
    float giz = pj[HH + u];
    float gin = pj[2*HH + u];

    const int4* hp = (const int4*)(&s_h[t & 1][0]);

    float ar0=0.f, ar1=0.f, az0=0.f, az1=0.f, an0=0.f, an1=0.f;
    DOTJ(0) DOTJ(1) DOTJ(2) DOTJ(3) DOTJ(4) DOTJ(5) DOTJ(6) DOTJ(7)

    // own-unit / other-unit partial selection, then quad reduction:
    // step 1 (xor2 via 0x4E): my k-quarter + partner's k-quarter of MY unit
    // step 2 (xor1 via 0xB1): combine the two k-halves
    float pr = sel ? ar1 : ar0,  qr = sel ? ar0 : ar1;
    float pz = sel ? az1 : az0,  qz = sel ? az0 : az1;
    float pn = sel ? an1 : an0,  qn = sel ? an0 : an1;
    pr += dpp4E(qr);  pz += dpp4E(qz);  pn += dpp4E(qn);
    pr += dppB1(pr);  pz += dppB1(pz);  pn += dppB1(pn);

    // gate chain, once per lane for unit u
    float r = 1.f / (1.f + __expf(-(gir + pr + bhr)));
    float z = 1.f / (1.f + __expf(-(giz + pz + bhz)));
    float x = gin + r * (pn + bhn);
    x = fminf(fmaxf(x, -15.f), 15.f);
    float e = __expf(2.f * x);
    float n = (e - 1.f) / (e + 1.f);     // tanh
    float hn = (1.f - z) * n + z * h_old;
    h_old = hn;

    // cross-lane partner values for packed stores
    float hn_o = dpp4E(hn);              // other unit's hn
    float z_o  = dpp4E(z);               // other unit's z

    if (lq == 0) {                       // publish h pair {u0,u1} (swizzled)
      h2 ph; ph.x = (_Float16)hn; ph.y = (_Float16)hn_o;
      ((unsigned*)(&s_h[(t + 1) & 1][0]))[pa] = __builtin_bit_cast(unsigned, ph);
    } else if (lq == 2) {                // outs f16 pair {u0,u1}
      h2 po; po.x = (_Float16)hn_o; po.y = (_Float16)hn;
      orow_u[(size_t)t * (HH/2)] = __builtin_bit_cast(unsigned, po);
    } else if (lq == 1) {                // beta pair {u0,u1}
      if (f32m) { float2 fz; fz.x = z; fz.y = z_o;
                  brow_f[(size_t)t * (HH/2)] = fz; }
      else      { unsigned pz2 = (unsigned)f2bf(z) | ((unsigned)f2bf(z_o) << 16);
                  brow_u[(size_t)t * (HH/2)] = pz2; }
    }
    bar_lds();   // lgkmcnt(0)+s_barrier; global stores stay in flight
  }
}

// ---------------------------------------------------------------------------
// k_head: logits = outs @ W_head + b_head.  outs is f16; W_head staged to LDS
// as packed h2 pairs (stride 129 h2 per output column -> no bank conflicts),
// inner loop is 128 fdot2.
// ---------------------------------------------------------------------------
#define WSTR 129

template<typename T>
__device__ __forceinline__ void stage_head(const T* W_head, const T* b_head,
                                           h2* s_w, float* s_b, int tid){
  for (int i = tid; i < NOUT * 128; i += 256) {
    int o = i >> 7, ip = i & 127;
    h2 pr;
    pr.x = (_Float16)ld1(W_head, (size_t)(2*ip    ) * NOUT + o);
    pr.y = (_Float16)ld1(W_head, (size_t)(2*ip + 1) * NOUT + o);
    s_w[o * WSTR + ip] = pr;
  }
  if (tid < NOUT) s_b[tid] = ld1(b_head, (size_t)tid);
}

__global__ __launch_bounds__(256) void k_head(
    const _Float16* __restrict__ outs,
    const void* __restrict__ W_head,
    const void* __restrict__ b_head,
    const void* __restrict__ W_ih,
    void* __restrict__ logits_out)
{
  __shared__ h2 s_w[NOUT * WSTR];
  __shared__ float s_b[NOUT];
  const bool f32m = detect_f32(W_ih);
  const int tid = threadIdx.x;

  if (f32m) stage_head<float>((const float*)W_head, (const float*)b_head,
                              s_w, s_b, tid);
  else      stage_head<unsigned short>((const unsigned short*)W_head,
                                       (const unsigned short*)b_head,
                                       s_w, s_b, tid);
  __syncthreads();

  size_t gid = (size_t)blockIdx.x * 256 + tid;
  if (gid >= LOGITS_ELEMS) return;
  int o = (int)(gid % NOUT);
  size_t row = gid / NOUT;

  const uint4* xp = (const uint4*)(outs + row * HH);
  const h2* wv = s_w + o * WSTR;
  float a0 = 0.f, a1 = 0.f, a2 = 0.f, a3 = 0.f;
  #pragma unroll 8
  for (int kk = 0; kk < 32; kk++) {
    uint4 uu = xp[kk];
    int kb = kk * 4;
    a0 = FDOT2(bch2(uu.x), wv[kb+0], a0);
    a1 = FDOT2(bch2(uu.y), wv[kb+1], a1);
    a2 = FDOT2(bch2(uu.z), wv[kb+2], a2);
    a3 = FDOT2(bch2(uu.w), wv[kb+3], a3);
  }
  float val = ((a0 + a1) + (a2 + a3)) + s_b[o];
  if (f32m) ((float*)logits_out)[gid] = val;
  else      ((unsigned short*)logits_out)[gid] = f2bf(val);
}

// ---------------------------------------------------------------------------
extern "C" void kernel_launch(void* const* d_in, const int* in_sizes, int n_in,
                              void* d_out, int out_size, void* d_ws, size_t ws_size,
                              hipStream_t stream)
{
  // inputs: tokens, embed, W_ih, W_hh, b_ih, b_hh, W_head, b_head
  const int* tokens = (const int*)d_in[0];
  const void* embed  = d_in[1];
  const void* W_ih   = d_in[2];
  const void* W_hh   = d_in[3];
  const void* b_ih   = d_in[4];
  const void* b_hh   = d_in[5];
  const void* W_head = d_in[6];
  const void* b_head = d_in[7];

  // workspace layout (16B aligned):
  // proj: 13824 f32 = 55296 B | bb: 768 f32 = 3072 B | Wp: 24576 float4 = 393216 B | outs (f16)
  char* ws = (char*)d_ws;
  float*    proj = (float*)ws;
  float*    bb   = (float*)(ws + 55296);
  float4*   Wp4  = (float4*)(ws + 55296 + 3072);
  _Float16* outs = (_Float16*)(ws + 55296 + 3072 + 393216);

  k_prep<<<96, 256, 0, stream>>>(W_hh, W_ih, Wp4);
  k_proj<<<NVOC, G3, 0, stream>>>(embed, W_ih, b_ih, b_hh, proj, bb);
  k_scan<<<BB, 512, 0, stream>>>(tokens, Wp4, bb, W_ih, proj, outs, d_out);
  k_head<<<(int)((LOGITS_ELEMS + 255) / 256), 256, 0, stream>>>(
      outs, W_head, b_head, W_ih, d_out);
}